// Round 1
// 343.545 us; speedup vs baseline: 1.0352x; 1.0352x over previous
//
#include <hip/hip_runtime.h>
#include <math.h>
#include <limits.h>

// ---- problem constants ----
#define C_IN 256
#define HM_H 136
#define HM_W 240
#define HM_N (HM_H * HM_W)      // 32640
#define MB   64
#define MH   272
#define MW   480
#define MN   (MH * MW)          // 130560
#define NP   134
#define NI   4
#define HID  64

// d_out layout (floats): scores[4] | inds[4] | regs0[4*MN] | masks0[4*MN] | feat[4*480*2]
#define REG_OFF   8
#define MASK_OFF  (8 + NI * MN)
#define FEAT_OFF  (8 + 2 * NI * MN)

// ws layout (floats): hm[32640] | cand_v[512]+cand_i[512] | gp[536] | wt @ 65824
#define WS_HM   0
#define WS_CV   HM_N
#define WS_CI   (HM_N + 512)
#define WS_GP   (2 * HM_N)
#define WS_WT_F 65824

typedef float  f32x4  __attribute__((ext_vector_type(4)));
typedef short  bf16x8 __attribute__((ext_vector_type(8)));
typedef unsigned short u16x4 __attribute__((ext_vector_type(4)));

__device__ __forceinline__ unsigned short f2bf(float f) {
  unsigned int u = __float_as_uint(f);
  u += 0x7FFFu + ((u >> 16) & 1u);
  return (unsigned short)(u >> 16);
}
__device__ __forceinline__ float b2f(unsigned short h) {
  return __uint_as_float(((unsigned int)h) << 16);
}

// ------------------------------------------------------------------
// K0: merged weight-prep + heatmap.
//   blocks [0,576): swizzle mb_w (OIHW fp32) into bf16 MFMA B-fragment order.
//   blocks [576,1086): hm = clip(sigmoid(hm_w . out1 + hm_b))
// ------------------------------------------------------------------
__global__ void k_prep(const float* __restrict__ mb_w, unsigned short* __restrict__ wt,
                       const float* __restrict__ out1, const float* __restrict__ hm_w,
                       const float* __restrict__ hm_b, float* __restrict__ ws_hm) {
  __shared__ float part[4][64];
  if (blockIdx.x < 576) {
    int idx = blockIdx.x * 256 + threadIdx.x;     // 147456 total
    int j    = idx & 7;
    int lane = (idx >> 3) & 63;
    int nt   = (idx >> 9) & 3;
    int gt   = idx >> 11;
    int t    = gt % 9;
    int g    = gt / 9;
    int n = nt * 16 + (lane & 15);
    int c = g * 32 + (lane >> 4) * 8 + j;
    wt[idx] = f2bf(mb_w[(n * C_IN + c) * 9 + t]);
  } else {
    int b = blockIdx.x - 576, t = threadIdx.x;
    int cg = t >> 6, pl = t & 63;
    int p = b * 64 + pl;                         // 510*64 = 32640
    float s = 0.f;
    #pragma unroll 16
    for (int c = 0; c < 64; ++c)
      s += hm_w[cg * 64 + c] * out1[(cg * 64 + c) * HM_N + p];
    part[cg][pl] = s;
    __syncthreads();
    if (t < 64) {
      float tot = part[0][t] + part[1][t] + part[2][t] + part[3][t] + hm_b[0];
      float sig = 1.f / (1.f + expf(-tot));
      sig = fminf(fmaxf(sig, 1e-4f), 1.f - 1e-4f);
      ws_hm[b * 64 + t] = sig;
    }
  }
}

// ------------------------------------------------------------------
// top-4 list merge helpers
// ------------------------------------------------------------------
__device__ __forceinline__ bool better(float av, int ai, float bv, int bi) {
  return (av > bv) || (av == bv && ai < bi);
}

// tree-merge top4 lists held in LDS (NTHR entries of 4), result at entry 0.
// Safe to call with >= NTHR threads (extras just hit the barriers).
template<int NTHR>
__device__ void top4_tree(float* sv, int* si, int t) {
  for (int s = NTHR / 2; s >= 1; s >>= 1) {
    if (t < s) {
      float a[4], b[4]; int ai[4], bj[4];
      #pragma unroll
      for (int k = 0; k < 4; ++k) {
        a[k] = sv[t * 4 + k];        ai[k] = si[t * 4 + k];
        b[k] = sv[(t + s) * 4 + k];  bj[k] = si[(t + s) * 4 + k];
      }
      float ov[4]; int oi[4];
      int i = 0, j = 0;
      #pragma unroll
      for (int k = 0; k < 4; ++k) {
        if (better(a[i], ai[i], b[j], bj[j])) { ov[k] = a[i]; oi[k] = ai[i]; ++i; }
        else                                   { ov[k] = b[j]; oi[k] = bj[j]; ++j; }
      }
      #pragma unroll
      for (int k = 0; k < 4; ++k) { sv[t * 4 + k] = ov[k]; si[t * 4 + k] = oi[k]; }
    }
    __syncthreads();
  }
}

// ------------------------------------------------------------------
// K2a: fused NMS + per-block top-4 (128 blocks x 255 pixels)
// ------------------------------------------------------------------
__global__ void k_nms_top(const float* __restrict__ ws_hm, float* __restrict__ candv,
                          int* __restrict__ candi) {
  __shared__ float sv[256 * 4];
  __shared__ int   si[256 * 4];
  int b = blockIdx.x, t = threadIdx.x;
  float v = -1.f; int idx = INT_MAX;
  if (t < 255) {
    int p = b * 255 + t;
    int y = p / HM_W, x = p - y * HM_W;
    float c = ws_hm[p], m = c;
    #pragma unroll
    for (int dy = -1; dy <= 1; ++dy)
      #pragma unroll
      for (int dx = -1; dx <= 1; ++dx) {
        int yy = y + dy, xx = x + dx;
        if (yy >= 0 && yy < HM_H && xx >= 0 && xx < HM_W)
          m = fmaxf(m, ws_hm[yy * HM_W + xx]);
      }
    v = (c == m) ? c : 0.f;
    idx = p;
  }
  sv[t * 4] = v; si[t * 4] = idx;
  #pragma unroll
  for (int k = 1; k < 4; ++k) { sv[t * 4 + k] = -1.f; si[t * 4 + k] = INT_MAX; }
  __syncthreads();
  top4_tree<256>(sv, si, t);
  if (t == 0) {
    #pragma unroll
    for (int k = 0; k < 4; ++k) { candv[b * 4 + k] = sv[k]; candi[b * 4 + k] = si[k]; }
  }
}

// ------------------------------------------------------------------
// K3: merged final top-k merge (done redundantly per block, deterministic)
//     + gen_params for the 4 winners. Block i handles instance i.
// ------------------------------------------------------------------
__global__ void k_gen(const float* __restrict__ candv, const int* __restrict__ candi,
                      const float* __restrict__ out1, const float* __restrict__ params_w,
                      const float* __restrict__ params_b, float* __restrict__ ws_gp,
                      float* __restrict__ d_out) {
  __shared__ float sv[128 * 4];
  __shared__ int   si[128 * 4];
  __shared__ float col[C_IN];
  int t = threadIdx.x, i = blockIdx.x;
  if (t < 128) {
    #pragma unroll
    for (int k = 0; k < 4; ++k) { sv[t * 4 + k] = candv[t * 4 + k]; si[t * 4 + k] = candi[t * 4 + k]; }
  }
  __syncthreads();
  top4_tree<128>(sv, si, t);
  if (i == 0 && t < 4) {
    d_out[t]     = sv[t];
    d_out[4 + t] = (float)si[t];
  }
  int p = si[i];
  col[t] = out1[t * HM_N + p];
  __syncthreads();
  if (t < NP) {
    float s = params_b[t];
    #pragma unroll 8
    for (int c = 0; c < C_IN; ++c) s += params_w[t * C_IN + c] * col[c];
    ws_gp[i * NP + t] = s;
  }
}

// ------------------------------------------------------------------
// K4: MFMA implicit-GEMM conv, double-buffered LDS staging.
// v2: 512 threads (8 waves x 2 mt-tiles), float4 staging + in-register
//     4x4 transpose -> ds_write_b64, CS=32 with XOR swizzle
//     (granule16 = 4*pix + (kq ^ ((pix^(pix>>2))&3))) on both write & read.
// ------------------------------------------------------------------
#define CSU 32                 // ushorts per pixel slot (power of 2)
#define RP  36                 // stored x positions per row (xloc 0..35 <-> gx0-1..gx0+34)
#define BUFU (10 * RP * CSU)   // 11520 ushorts = 23040 B per buffer

__device__ __forceinline__ void stage_store(unsigned short* buf, const f32x4* dq,
                                            bool gv, const int* lw, unsigned sm) {
  #pragma unroll
  for (int e = 0; e < 4; ++e) if ((sm >> e) & 1u) {
    u16x4 v;
    v[0] = f2bf(gv ? dq[0][e] : 0.f);
    v[1] = f2bf(gv ? dq[1][e] : 0.f);
    v[2] = f2bf(gv ? dq[2][e] : 0.f);
    v[3] = f2bf(gv ? dq[3][e] : 0.f);
    *(u16x4*)(buf + lw[e]) = v;
  }
}

__global__ __launch_bounds__(512, 3) void k_conv_mfma(
    const float* __restrict__ out0, const unsigned short* __restrict__ wt,
    const float* __restrict__ mb_b, const float* __restrict__ ws_gp,
    float* __restrict__ d_out) {
  __shared__ unsigned short smem[2 * BUFU];   // 46080 B

  int tid  = threadIdx.x;
  int lane = tid & 63;
  int wv   = tid >> 6;       // wave 0..7
  int n15  = lane & 15;
  int kq   = lane >> 4;
  int gx0 = blockIdx.x * 32, gy0 = blockIdx.y * 8;

  // --- staging descriptors: 800 units of (row, qx, cq4); unit = 4x float4 -> 4x b64 ---
  int goff[2]; int lws[2][4]; unsigned smask[2]; bool gvld[2];
  #pragma unroll
  for (int kk = 0; kk < 2; ++kk) {
    int u = tid + 512 * kk;
    bool uv = (u < 800);
    int uu = uv ? u : 0;
    int cq  = uu / 100;
    int rem = uu - cq * 100;
    int row = rem / 10;
    int qx  = rem - row * 10;
    int iy  = gy0 + row - 1;
    int ixq = gx0 + 4 * qx - 4;               // 16B-aligned quad
    bool v = uv && (iy >= 0) && (iy < MH) && (ixq >= 0) && (ixq + 3 < MW);
    gvld[kk] = v;
    goff[kk] = v ? (cq * 4 * MN + iy * MW + ixq) : 0;
    unsigned sm = 0;
    #pragma unroll
    for (int e = 0; e < 4; ++e) {
      int sx = 4 * qx - 3 + e;                // stored x index
      bool s = uv && (sx >= 0) && (sx < RP);
      int sxc = s ? sx : 0;
      int pix = row * RP + sxc;
      int w2  = (pix ^ (pix >> 2)) & 3;
      lws[kk][e] = s ? ((pix << 5) + ((cq ^ (w2 << 1)) << 2)) : 0;
      if (s) sm |= (1u << e);
    }
    smask[kk] = sm;
  }

  // --- A-frag LDS read offsets (per tap); second sub-tile = +16 pixels = +512 ushorts ---
  int lrd[9];
  #pragma unroll
  for (int t = 0; t < 9; ++t) {
    int ty = t / 3, tx = t - ty * 3;
    int pix = (wv + ty) * RP + n15 + tx;
    int w2  = (pix ^ (pix >> 2)) & 3;
    lrd[t] = (pix << 5) + ((kq ^ w2) << 3);
  }

  // --- prologue: stage ch-group 0 into buf0 ---
  {
    f32x4 dq[4];
    {
      const float* sp = out0 + goff[0];
      #pragma unroll
      for (int j = 0; j < 4; ++j) dq[j] = *(const f32x4*)(sp + j * MN);
      stage_store(smem, dq, gvld[0], lws[0], smask[0]);
    }
    if (tid < 288) {
      const float* sp = out0 + goff[1];
      #pragma unroll
      for (int j = 0; j < 4; ++j) dq[j] = *(const f32x4*)(sp + j * MN);
      stage_store(smem, dq, gvld[1], lws[1], smask[1]);
    }
  }
  __syncthreads();

  f32x4 acc[2][4];
  #pragma unroll
  for (int i = 0; i < 2; ++i)
    #pragma unroll
    for (int nt = 0; nt < 4; ++nt)
      acc[i][nt] = (f32x4){0.f, 0.f, 0.f, 0.f};

  #pragma unroll 1
  for (int g = 0; g < 8; ++g) {
    const unsigned short* cur = smem + (g & 1) * BUFU;
    unsigned short*       nxt = smem + ((g + 1) & 1) * BUFU;
    const float*          src = out0 + (g + 1) * (32 * MN);
    f32x4 dqa[4], dqb[4];

    if (g < 7) {
      const float* sp = src + goff[0];
      #pragma unroll
      for (int j = 0; j < 4; ++j) dqa[j] = *(const f32x4*)(sp + j * MN);
    }
    #pragma unroll
    for (int t = 0; t < 4; ++t) {
      const unsigned short* wb = wt + (g * 9 + t) * 2048 + lane * 8;
      bf16x8 bf[4];
      #pragma unroll
      for (int nt = 0; nt < 4; ++nt) bf[nt] = *(const bf16x8*)(wb + nt * 512);
      bf16x8 a0 = *(const bf16x8*)&cur[lrd[t]];
      bf16x8 a1 = *(const bf16x8*)&cur[lrd[t] + 512];
      #pragma unroll
      for (int nt = 0; nt < 4; ++nt) {
        acc[0][nt] = __builtin_amdgcn_mfma_f32_16x16x32_bf16(a0, bf[nt], acc[0][nt], 0, 0, 0);
        acc[1][nt] = __builtin_amdgcn_mfma_f32_16x16x32_bf16(a1, bf[nt], acc[1][nt], 0, 0, 0);
      }
    }
    if (g < 7) {
      stage_store(nxt, dqa, gvld[0], lws[0], smask[0]);
      if (tid < 288) {
        const float* sp = src + goff[1];
        #pragma unroll
        for (int j = 0; j < 4; ++j) dqb[j] = *(const f32x4*)(sp + j * MN);
      }
    }
    #pragma unroll
    for (int t = 4; t < 9; ++t) {
      const unsigned short* wb = wt + (g * 9 + t) * 2048 + lane * 8;
      bf16x8 bf[4];
      #pragma unroll
      for (int nt = 0; nt < 4; ++nt) bf[nt] = *(const bf16x8*)(wb + nt * 512);
      bf16x8 a0 = *(const bf16x8*)&cur[lrd[t]];
      bf16x8 a1 = *(const bf16x8*)&cur[lrd[t] + 512];
      #pragma unroll
      for (int nt = 0; nt < 4; ++nt) {
        acc[0][nt] = __builtin_amdgcn_mfma_f32_16x16x32_bf16(a0, bf[nt], acc[0][nt], 0, 0, 0);
        acc[1][nt] = __builtin_amdgcn_mfma_f32_16x16x32_bf16(a1, bf[nt], acc[1][nt], 0, 0, 0);
      }
    }
    if (g < 7 && tid < 288) stage_store(nxt, dqb, gvld[1], lws[1], smask[1]);
    __syncthreads();
  }

  // --- epilogue: bias+relu, acc -> LDS [pixel][channel] bf16 ---
  #define ES 66
  {
    float bias[4];
    #pragma unroll
    for (int nt = 0; nt < 4; ++nt) bias[nt] = mb_b[nt * 16 + n15];
    #pragma unroll
    for (int i = 0; i < 2; ++i) {
      int pbase = wv * 32 + i * 16;
      #pragma unroll
      for (int nt = 0; nt < 4; ++nt)
        #pragma unroll
        for (int reg = 0; reg < 4; ++reg) {
          float vv = fmaxf(acc[i][nt][reg] + bias[nt], 0.f);
          smem[(pbase + kq * 4 + reg) * ES + nt * 16 + n15] = f2bf(vv);
        }
    }
  }
  __syncthreads();

  // dynamic heads: thread (p, half) handles pixel p, channels [half*32, half*32+32)
  int p = tid & 255, hh = tid >> 8;
  int ob = hh * 32;
  float mres[4] = {0.f, 0.f, 0.f, 0.f};
  float rres[4] = {0.f, 0.f, 0.f, 0.f};
  #pragma unroll 8
  for (int o = 0; o < 32; ++o) {
    float v = b2f(smem[p * ES + ob + o]);
    #pragma unroll
    for (int i = 0; i < 4; ++i) {
      mres[i] += ws_gp[i * NP + ob + o] * v;
      rres[i] += ws_gp[i * NP + 67 + ob + o] * v;
    }
  }
  float* pf = (float*)smem + 8704;   // byte 34816, past ES table (33792 B)
  if (hh) {
    #pragma unroll
    for (int i = 0; i < 4; ++i) { pf[p * 8 + i] = mres[i]; pf[p * 8 + 4 + i] = rres[i]; }
  }
  __syncthreads();
  if (!hh) {
    int r = p >> 5, xcol = p & 31;
    int gy = gy0 + r, gx = gx0 + xcol;
    float xc = -1.f + (2.f / 479.f) * (float)gx;
    float yc = -1.f + (2.f / 271.f) * (float)gy;
    int pix = gy * MW + gx;
    #pragma unroll
    for (int i = 0; i < 4; ++i) {
      const float* gp = ws_gp + i * NP;
      d_out[MASK_OFF + i * MN + pix] = mres[i] + pf[p * 8 + i]     + gp[66]  + gp[64]  * xc + gp[65]  * yc;
      d_out[REG_OFF  + i * MN + pix] = rres[i] + pf[p * 8 + 4 + i] + gp[133] + gp[131] * xc + gp[132] * yc;
    }
  }
}

// ------------------------------------------------------------------
// K5: feat_range MLP
// ------------------------------------------------------------------
__global__ void k_mlp(const float* __restrict__ masks0, const float* __restrict__ w1,
                      const float* __restrict__ b1, const float* __restrict__ w2,
                      const float* __restrict__ b2, float* __restrict__ d_out) {
  int blk = blockIdx.x;          // i*480 + w
  int i = blk / MW;
  int w = blk - i * MW;
  int k = threadIdx.x;           // 0..63
  const float* mcol = masks0 + i * MN + w;
  float s = b1[k];
  #pragma unroll 4
  for (int h = 0; h < MH; ++h) s += mcol[h * MW] * w1[h * HID + k];
  s = fmaxf(s, 0.f);
  float o0 = s * w2[k * 2 + 0];
  float o1 = s * w2[k * 2 + 1];
  #pragma unroll
  for (int off = 32; off >= 1; off >>= 1) {
    o0 += __shfl_down(o0, off);
    o1 += __shfl_down(o1, off);
  }
  if (k == 0) {
    d_out[FEAT_OFF + blk * 2 + 0] = o0 + b2[0];
    d_out[FEAT_OFF + blk * 2 + 1] = o1 + b2[1];
  }
}

// ------------------------------------------------------------------
extern "C" void kernel_launch(void* const* d_in, const int* in_sizes, int n_in,
                              void* d_out, int out_size, void* d_ws, size_t ws_size,
                              hipStream_t stream) {
  const float* out0     = (const float*)d_in[0];
  const float* out1     = (const float*)d_in[1];
  const float* hm_w     = (const float*)d_in[2];
  const float* hm_b     = (const float*)d_in[3];
  const float* params_w = (const float*)d_in[4];
  const float* params_b = (const float*)d_in[5];
  const float* mb_w     = (const float*)d_in[6];
  const float* mb_b     = (const float*)d_in[7];
  const float* mlp_w1   = (const float*)d_in[8];
  const float* mlp_b1   = (const float*)d_in[9];
  const float* mlp_w2   = (const float*)d_in[10];
  const float* mlp_b2   = (const float*)d_in[11];

  float* ws      = (float*)d_ws;
  float* ws_hm   = ws + WS_HM;
  float* candv   = ws + WS_CV;
  int*   candi   = (int*)(ws + WS_CI);
  float* ws_gp   = ws + WS_GP;
  unsigned short* ws_wt = (unsigned short*)(ws + WS_WT_F);
  float* out     = (float*)d_out;

  k_prep<<<1086, 256, 0, stream>>>(mb_w, ws_wt, out1, hm_w, hm_b, ws_hm);
  k_nms_top<<<128, 256, 0, stream>>>(ws_hm, candv, candi);
  k_gen<<<NI, 256, 0, stream>>>(candv, candi, out1, params_w, params_b, ws_gp, out);
  dim3 gconv(MW / 32, MH / 8);   // 15 x 34
  k_conv_mfma<<<gconv, 512, 0, stream>>>(out0, ws_wt, mb_b, ws_gp, out);
  k_mlp<<<NI * MW, 64, 0, stream>>>(out + MASK_OFF, mlp_w1, mlp_b1, mlp_w2, mlp_b2, out);
}